// Round 3
// baseline (36.930 us; speedup 1.0000x reference)
//
#include <hip/hip_runtime.h>
#include <math.h>

#define PI_F 3.14159265358979323846f

typedef float f32x2 __attribute__((ext_vector_type(2)));
typedef float f32x4 __attribute__((ext_vector_type(4)));

// ---------------------------------------------------------------------------
// Packed-FP32 helpers (CDNA v_pk_* — one instruction, two f32 lanes).
// Element A lives in .x (lo), element B in .y (hi) of every pair.
// ---------------------------------------------------------------------------
static __device__ __forceinline__ f32x2 pkmul(f32x2 a, f32x2 b) {
  f32x2 d;
  asm("v_pk_mul_f32 %0, %1, %2" : "=v"(d) : "v"(a), "v"(b));
  return d;
}
static __device__ __forceinline__ f32x2 pkadd(f32x2 a, f32x2 b) {
  f32x2 d;
  asm("v_pk_add_f32 %0, %1, %2" : "=v"(d) : "v"(a), "v"(b));
  return d;
}
static __device__ __forceinline__ f32x2 pksub(f32x2 a, f32x2 b) {
  f32x2 d;
  asm("v_pk_add_f32 %0, %1, %2 neg_lo:[0,1] neg_hi:[0,1]" : "=v"(d) : "v"(a), "v"(b));
  return d;
}
static __device__ __forceinline__ f32x2 pkfma(f32x2 a, f32x2 b, f32x2 c) {  // a*b+c
  f32x2 d;
  asm("v_pk_fma_f32 %0, %1, %2, %3" : "=v"(d) : "v"(a), "v"(b), "v"(c));
  return d;
}
static __device__ __forceinline__ f32x2 pkfman(f32x2 a, f32x2 b, f32x2 c) { // -a*b+c
  f32x2 d;
  asm("v_pk_fma_f32 %0, %1, %2, %3 neg_lo:[1,0,0] neg_hi:[1,0,0]" : "=v"(d) : "v"(a), "v"(b), "v"(c));
  return d;
}
static __device__ __forceinline__ f32x2 shfl_xor2(f32x2 v, int m) {
  f32x2 r; r.x = __shfl_xor(v.x, m, 64); r.y = __shfl_xor(v.y, m, 64); return r;
}
static __device__ __forceinline__ f32x2 bcast2(f32x2 v, int l) {
  f32x2 r; r.x = __shfl(v.x, l, 64); r.y = __shfl(v.y, l, 64); return r;
}
static __device__ __forceinline__ f32x2 dup2(float s) {
  f32x2 r; r.x = s; r.y = s; return r;
}

// ---------------------------------------------------------------------------
// Index algebra identical to R2 (verified): amplitude p = lane*4 + r,
// wires 0..5 = lane bits 5..0, wires 6,7 = r bits 1,0. CNOTs absorbed into
// gate masks via GF(2) relabeling (A1/A2 matrices, see R2 comments).
// ---------------------------------------------------------------------------
template<int LMASK, int RMASK, int HIL, int HIR>
__device__ __forceinline__ void applyG2(f32x2 ar[4], f32x2 ai[4],
                                        const f32x4* __restrict__ g4, int lane)
{
  const f32x4 ga = g4[0];  // u00r,u00r,u00i,u00i
  const f32x4 gb = g4[1];  // u01r,u01r,u01i,u01i
  const f32x4 gc = g4[2];  // u10r,u10r,u10i,u10i
  const f32x4 gd = g4[3];  // u11r,u11r,u11i,u11i
  const f32x2 u00r = __builtin_shufflevector(ga, ga, 0, 1);
  const f32x2 u00i = __builtin_shufflevector(ga, ga, 2, 3);
  const f32x2 u01r = __builtin_shufflevector(gb, gb, 0, 1);
  const f32x2 u01i = __builtin_shufflevector(gb, gb, 2, 3);
  const f32x2 u10r = __builtin_shufflevector(gc, gc, 0, 1);
  const f32x2 u10i = __builtin_shufflevector(gc, gc, 2, 3);
  const f32x2 u11r = __builtin_shufflevector(gd, gd, 0, 1);
  const f32x2 u11i = __builtin_shufflevector(gd, gd, 2, 3);

  bool pl = false;
  if constexpr (HIL != 0) pl = (__popc(lane & HIL) & 1) != 0;

  // coefficient sets for r-parity 0 / 1 (hi = pl ^ rp)
  f32x2 Ar[2], Ai[2], Br[2], Bi[2];
  Ar[0] = pl ? u11r : u00r;  Ai[0] = pl ? u11i : u00i;
  Br[0] = pl ? u10r : u01r;  Bi[0] = pl ? u10i : u01i;
  if constexpr (HIR != 0) {
    Ar[1] = pl ? u00r : u11r;  Ai[1] = pl ? u00i : u11i;
    Br[1] = pl ? u01r : u10r;  Bi[1] = pl ? u01i : u10i;
  } else {
    Ar[1] = Ar[0]; Ai[1] = Ai[0]; Br[1] = Br[0]; Bi[1] = Bi[0];
  }

  f32x2 nr[4], ni[4];
#pragma unroll
  for (int r = 0; r < 4; ++r) {
    const int hi = (__popc(r & HIR) & 1);
    const f32x2 sr = ar[r], si = ai[r];
    f32x2 pr, pi;
    if constexpr (LMASK != 0) {
      pr.x = __shfl_xor(ar[r ^ RMASK].x, LMASK, 64);
      pr.y = __shfl_xor(ar[r ^ RMASK].y, LMASK, 64);
      pi.x = __shfl_xor(ai[r ^ RMASK].x, LMASK, 64);
      pi.y = __shfl_xor(ai[r ^ RMASK].y, LMASK, 64);
    } else {
      pr = ar[r ^ RMASK]; pi = ai[r ^ RMASK];
    }
    // nr = Ar*sr - Ai*si + Br*pr - Bi*pi
    f32x2 t;
    t = pkmul (Ar[hi], sr);
    t = pkfman(Ai[hi], si, t);
    t = pkfma (Br[hi], pr, t);
    t = pkfman(Bi[hi], pi, t);
    nr[r] = t;
    // ni = Ar*si + Ai*sr + Br*pi + Bi*pr
    t = pkmul (Ar[hi], si);
    t = pkfma (Ai[hi], sr, t);
    t = pkfma (Br[hi], pi, t);
    t = pkfma (Bi[hi], pr, t);
    ni[r] = t;
  }
#pragma unroll
  for (int r = 0; r < 4; ++r) { ar[r] = nr[r]; ai[r] = ni[r]; }
}

// ---------------------------------------------------------------------------
// Setup: 16 fixed Rot matrices, each coefficient stored DUPLICATED
// (16 floats per gate) so the main kernel loads ready-made f32x2 pairs.
// ---------------------------------------------------------------------------
__global__ void qbranch_setup(const float* __restrict__ weights,
                              float* __restrict__ gates)
{
  int t = threadIdx.x;
  if (t >= 16) return;
  float phi = weights[t*3 + 0];
  float th  = weights[t*3 + 1];
  float om  = weights[t*3 + 2];
  float ct = cosf(th * 0.5f), st = sinf(th * 0.5f);
  float ap = (phi + om) * 0.5f, am = (phi - om) * 0.5f;
  float cap = cosf(ap), sap = sinf(ap);
  float cam = cosf(am), sam = sinf(am);
  float v0 =  cap*ct, v1 = -sap*ct;   // u00
  float v2 = -cam*st, v3 = -sam*st;   // u01
  float v4 =  cam*st, v5 = -sam*st;   // u10
  float v6 =  cap*ct, v7 =  sap*ct;   // u11
  float* g = gates + t*16;
  g[0]=v0;  g[1]=v0;  g[2]=v1;  g[3]=v1;
  g[4]=v2;  g[5]=v2;  g[6]=v3;  g[7]=v3;
  g[8]=v4;  g[9]=v4;  g[10]=v5; g[11]=v5;
  g[12]=v6; g[13]=v6; g[14]=v7; g[15]=v7;
}

// ---------------------------------------------------------------------------
// Main: 4 waves/block, TWO batch elements per wave (lo/hi halves of pairs).
// ---------------------------------------------------------------------------
__global__ __launch_bounds__(256) void qbranch_main(
    const float* __restrict__ x,     // (B,8)
    const float* __restrict__ gates, // 16 gates x 16 floats (duplicated pairs)
    const float* __restrict__ Wm,    // (8,64)
    const float* __restrict__ bias,  // (64)
    const float* __restrict__ gamma, // (64)
    const float* __restrict__ beta,  // (64)
    float* __restrict__ out,         // (B,64)
    int B)
{
  const int lane = threadIdx.x & 63;
  const int wid  = threadIdx.x >> 6;
  const int bA   = blockIdx.x * 8 + wid * 2;
  const int bB   = bA + 1;
  if (bA >= B) return;
  const int bBl  = (bB < B) ? bB : bA;   // safe load index

  // --- trig: lanes 0..15 -> element A (lane 2w: cos_w, 2w+1: sin_w),
  //           lanes 16..31 -> element B --------------------------------------
  float val = 0.f;
  if (lane < 32) {
    const int e = lane >> 4;
    const int t = lane & 15;
    float xv = x[(e ? bBl : bA)*8 + (t >> 1)];
    float th = 1.f - 2.f / (__expf(2.f*xv) + 1.f);   // tanh
    float ha = th * (PI_F * 0.5f);
    val = (t & 1) ? __sinf(ha) : __cosf(ha);
  }

  const int l5=(lane>>5)&1, l4=(lane>>4)&1, l3=(lane>>3)&1,
            l2=(lane>>2)&1, l1=(lane>>1)&1, l0=lane&1;
  float m0A=__shfl(val, 0+l5,64), m0B=__shfl(val,16+ 0+l5,64);
  float m1A=__shfl(val, 2+l4,64), m1B=__shfl(val,16+ 2+l4,64);
  float m2A=__shfl(val, 4+l3,64), m2B=__shfl(val,16+ 4+l3,64);
  float m3A=__shfl(val, 6+l2,64), m3B=__shfl(val,16+ 6+l2,64);
  float m4A=__shfl(val, 8+l1,64), m4B=__shfl(val,16+ 8+l1,64);
  float m5A=__shfl(val,10+l0,64), m5B=__shfl(val,16+10+l0,64);
  float c6A=__shfl(val,12,64), s6A=__shfl(val,13,64);
  float c7A=__shfl(val,14,64), s7A=__shfl(val,15,64);
  float c6B=__shfl(val,28,64), s6B=__shfl(val,29,64);
  float c7B=__shfl(val,30,64), s7B=__shfl(val,31,64);

  const float pA = m0A*m1A*m2A*m3A*m4A*m5A;
  const float pB = m0B*m1B*m2B*m3B*m4B*m5B;
  f32x2 mag[4];
  mag[0].x = pA*c6A*c7A;  mag[0].y = pB*c6B*c7B;
  mag[1].x = pA*c6A*s7A;  mag[1].y = pB*c6B*s7B;
  mag[2].x = pA*s6A*c7A;  mag[2].y = pB*s6B*c7B;
  mag[3].x = pA*s6A*s7A;  mag[3].y = pB*s6B*s7B;

  // product state: amp(p) = mag(p) * (-i)^popc(p)
  f32x2 ar[4], ai[4];
  {
    const int kl = __popc(lane);
    const f32x2 zero = {0.f, 0.f};
#pragma unroll
    for (int r = 0; r < 4; ++r) {
      const int k = kl + ((r >> 1) & 1) + (r & 1);
      f32x2 sgn = (k & 2) ? -mag[r] : mag[r];
      ar[r] = (k & 1) ? zero : sgn;
      ai[r] = (k & 1) ? -sgn : zero;
    }
  }

  const f32x4* G = (const f32x4*)gates;

  // --- layer 0 Rot gates (A = I) ------------------------------------------
  applyG2<0x20, 0, 0x20, 0>(ar, ai, G +  0*4, lane);
  applyG2<0x10, 0, 0x10, 0>(ar, ai, G +  1*4, lane);
  applyG2<0x08, 0, 0x08, 0>(ar, ai, G +  2*4, lane);
  applyG2<0x04, 0, 0x04, 0>(ar, ai, G +  3*4, lane);
  applyG2<0x02, 0, 0x02, 0>(ar, ai, G +  4*4, lane);
  applyG2<0x01, 0, 0x01, 0>(ar, ai, G +  5*4, lane);
  applyG2<0x00, 2, 0x00, 2>(ar, ai, G +  6*4, lane);
  applyG2<0x00, 1, 0x00, 1>(ar, ai, G +  7*4, lane);

  // --- layer 1 Rot gates (CNOT ring r=1 absorbed) -------------------------
  applyG2<0x30, 0, 0x1F, 3>(ar, ai, G +  8*4, lane);
  applyG2<0x18, 0, 0x30, 0>(ar, ai, G +  9*4, lane);
  applyG2<0x0C, 0, 0x38, 0>(ar, ai, G + 10*4, lane);
  applyG2<0x06, 0, 0x3C, 0>(ar, ai, G + 11*4, lane);
  applyG2<0x03, 0, 0x3E, 0>(ar, ai, G + 12*4, lane);
  applyG2<0x01, 2, 0x3F, 0>(ar, ai, G + 13*4, lane);
  applyG2<0x00, 3, 0x3F, 2>(ar, ai, G + 14*4, lane);
  applyG2<0x30, 1, 0x3F, 3>(ar, ai, G + 15*4, lane);

  // --- Z expectations with A2 sign masks ----------------------------------
  f32x2 pp0 = pkfma(ar[0], ar[0], pkmul(ai[0], ai[0]));
  f32x2 pp1 = pkfma(ar[1], ar[1], pkmul(ai[1], ai[1]));
  f32x2 pp2 = pkfma(ar[2], ar[2], pkmul(ai[2], ai[2]));
  f32x2 pp3 = pkfma(ar[3], ar[3], pkmul(ai[3], ai[3]));
  f32x2 s01 = pkadd(pp0, pp1), d01 = pksub(pp0, pp1);
  f32x2 s23 = pkadd(pp2, pp3), d23 = pksub(pp2, pp3);
  f32x2 q0 = pkadd(s01, s23);
  f32x2 q1 = pkadd(d01, d23);
  f32x2 q2 = pksub(s01, s23);
  f32x2 q3 = pksub(d01, d23);
  f32x2 n0 = -q0, n1 = -q1, n2 = -q2, n3 = -q3;

  f32x2 zp[8];
  zp[0] = (__popc(lane & 0x39) & 1) ? n2 : q2;
  zp[1] = (__popc(lane & 0x3C) & 1) ? n3 : q3;
  zp[2] = (__popc(lane & 0x27) & 1) ? n3 : q3;
  zp[3] = (__popc(lane & 0x0C) & 1) ? n0 : q0;
  zp[4] = (__popc(lane & 0x19) & 1) ? n3 : q3;
  zp[5] = (__popc(lane & 0x33) & 1) ? n0 : q0;
  zp[6] = (__popc(lane & 0x26) & 1) ? n1 : q1;
  zp[7] = (__popc(lane & 0x0C) & 1) ? n3 : q3;

  // --- split-butterfly reduce: lane ends with z_{4*b0+2*b1+b2} ------------
  const bool lb0 = (lane & 1) != 0, lb1 = (lane & 2) != 0, lb2 = (lane & 4) != 0;
  f32x2 u[4];
#pragma unroll
  for (int k = 0; k < 4; ++k) {
    f32x2 snd = lb0 ? zp[k] : zp[k+4];
    f32x2 rcv = shfl_xor2(snd, 1);
    u[k] = pkadd(lb0 ? zp[k+4] : zp[k], rcv);
  }
  f32x2 v2[2];
#pragma unroll
  for (int k = 0; k < 2; ++k) {
    f32x2 snd = lb1 ? u[k] : u[k+2];
    f32x2 rcv = shfl_xor2(snd, 2);
    v2[k] = pkadd(lb1 ? u[k+2] : u[k], rcv);
  }
  f32x2 snd3 = lb2 ? v2[0] : v2[1];
  f32x2 zs = pkadd(lb2 ? v2[1] : v2[0], shfl_xor2(snd3, 4));
  zs = pkadd(zs, shfl_xor2(zs,  8));
  zs = pkadd(zs, shfl_xor2(zs, 16));
  zs = pkadd(zs, shfl_xor2(zs, 32));

  const f32x2 z0 = bcast2(zs, 0);
  const f32x2 z1 = bcast2(zs, 4);
  const f32x2 z2 = bcast2(zs, 2);
  const f32x2 z3 = bcast2(zs, 6);
  const f32x2 z4 = bcast2(zs, 1);
  const f32x2 z5 = bcast2(zs, 5);
  const f32x2 z6 = bcast2(zs, 3);
  const f32x2 z7 = bcast2(zs, 7);

  // --- projection (8 -> 64), lane j computes h[j] for both elements -------
  const int j = lane;
  f32x2 h = dup2(bias[j]);
  h = pkfma(dup2(Wm[0*64 + j]), z0, h);
  h = pkfma(dup2(Wm[1*64 + j]), z1, h);
  h = pkfma(dup2(Wm[2*64 + j]), z2, h);
  h = pkfma(dup2(Wm[3*64 + j]), z3, h);
  h = pkfma(dup2(Wm[4*64 + j]), z4, h);
  h = pkfma(dup2(Wm[5*64 + j]), z5, h);
  h = pkfma(dup2(Wm[6*64 + j]), z6, h);
  h = pkfma(dup2(Wm[7*64 + j]), z7, h);

  // --- LayerNorm: fused sum/sumsq butterfly -------------------------------
  f32x2 S = h, Q = pkmul(h, h);
  f32x2 snd4 = lb0 ? S : Q;
  f32x2 rcv4 = shfl_xor2(snd4, 1);
  f32x2 acc = pkadd(lb0 ? Q : S, rcv4);
  acc = pkadd(acc, shfl_xor2(acc,  2));
  acc = pkadd(acc, shfl_xor2(acc,  4));
  acc = pkadd(acc, shfl_xor2(acc,  8));
  acc = pkadd(acc, shfl_xor2(acc, 16));
  acc = pkadd(acc, shfl_xor2(acc, 32));
  const f32x2 Ssum = bcast2(acc, 0);
  const f32x2 Qsum = bcast2(acc, 1);
  const f32x2 inv64 = dup2(1.f/64.f);
  f32x2 mu  = pkmul(Ssum, inv64);
  f32x2 var = pkfman(mu, mu, pkmul(Qsum, inv64));   // E[x^2] - mu^2
  f32x2 d   = pksub(h, mu);
  f32x2 rs;
  rs.x = rsqrtf(var.x + 1e-5f);
  rs.y = rsqrtf(var.y + 1e-5f);
  f32x2 o = pkfma(pkmul(dup2(gamma[j]), d), rs, dup2(beta[j]));

  out[bA*64 + j] = o.x;
  if (bB < B) out[bB*64 + j] = o.y;
}

// ---------------------------------------------------------------------------
extern "C" void kernel_launch(void* const* d_in, const int* in_sizes, int n_in,
                              void* d_out, int out_size, void* d_ws, size_t ws_size,
                              hipStream_t stream)
{
  const float* x       = (const float*)d_in[0];
  const float* weights = (const float*)d_in[1];
  const float* Wm      = (const float*)d_in[2];
  const float* bias    = (const float*)d_in[3];
  const float* gamma   = (const float*)d_in[4];
  const float* beta    = (const float*)d_in[5];
  float* out   = (float*)d_out;
  float* gates = (float*)d_ws;   // 16 gates * 16 floats = 1 KiB

  const int B = in_sizes[0] / 8;

  hipLaunchKernelGGL(qbranch_setup, dim3(1), dim3(64), 0, stream, weights, gates);
  hipLaunchKernelGGL(qbranch_main, dim3((B + 7) / 8), dim3(256), 0, stream,
                     x, gates, Wm, bias, gamma, beta, out, B);
}

// Round 5
// 32.640 us; speedup vs baseline: 1.1314x; 1.1314x over previous
//
#include <hip/hip_runtime.h>
#include <math.h>

#define PI_F 3.14159265358979323846f

typedef float f32x2 __attribute__((ext_vector_type(2)));
typedef float f32x4 __attribute__((ext_vector_type(4)));
typedef int   i32x2 __attribute__((ext_vector_type(2)));

// ---------------------------------------------------------------------------
// Packed-FP32 helpers (v_pk_* — one instruction, two f32 lanes).
// ---------------------------------------------------------------------------
static __device__ __forceinline__ f32x2 pkmul(f32x2 a, f32x2 b) {
  f32x2 d; asm("v_pk_mul_f32 %0, %1, %2" : "=v"(d) : "v"(a), "v"(b)); return d;
}
static __device__ __forceinline__ f32x2 pkadd(f32x2 a, f32x2 b) {
  f32x2 d; asm("v_pk_add_f32 %0, %1, %2" : "=v"(d) : "v"(a), "v"(b)); return d;
}
static __device__ __forceinline__ f32x2 pksub(f32x2 a, f32x2 b) {
  f32x2 d; asm("v_pk_add_f32 %0, %1, %2 neg_lo:[0,1] neg_hi:[0,1]" : "=v"(d) : "v"(a), "v"(b)); return d;
}
static __device__ __forceinline__ f32x2 pkfma(f32x2 a, f32x2 b, f32x2 c) {  // a*b+c
  f32x2 d; asm("v_pk_fma_f32 %0, %1, %2, %3" : "=v"(d) : "v"(a), "v"(b), "v"(c)); return d;
}
static __device__ __forceinline__ f32x2 pkfman(f32x2 a, f32x2 b, f32x2 c) { // -a*b+c
  f32x2 d; asm("v_pk_fma_f32 %0, %1, %2, %3 neg_lo:[1,0,0] neg_hi:[1,0,0]" : "=v"(d) : "v"(a), "v"(b), "v"(c)); return d;
}
template<bool NEG>
static __device__ __forceinline__ f32x2 pkfma_s(f32x2 a, f32x2 b, f32x2 c) {
  if constexpr (NEG) return pkfman(a, b, c); else return pkfma(a, b, c);
}
static __device__ __forceinline__ f32x2 dup2(float s) { f32x2 r; r.x = s; r.y = s; return r; }

// ---------------------------------------------------------------------------
// Cross-lane exchange primitives — routed OFF the LDS pipe where possible.
// dpp ctrl: quad_perm[1,0,3,2]=0xB1 (xor1), [2,3,0,1]=0x4E (xor2),
//           [3,2,1,0]=0x1B (xor3), row_half_mirror=0x141 (xor7),
//           row_ror:8=0x128 (xor8).
// ds_swizzle BitMode offset = (xor<<10)|(or<<5)|and.
// ---------------------------------------------------------------------------
template<int CTRL>
static __device__ __forceinline__ float dppf(float v) {
  return __builtin_bit_cast(float,
    __builtin_amdgcn_update_dpp(0, __builtin_bit_cast(int, v), CTRL, 0xF, 0xF, false));
}
template<int OFF>
static __device__ __forceinline__ float swzf(float v) {
  return __builtin_bit_cast(float,
    __builtin_amdgcn_ds_swizzle(__builtin_bit_cast(int, v), OFF));
}
static __device__ __forceinline__ float pswap32(float v, bool hi) {
  // v_permlane32_swap_b32 vdst,vsrc swaps vdst.hi32 <-> vsrc.lo32.
  // With both = v:  r.x[l<32]=v[l], r.x[l>=32]=v[l-32];
  //                 r.y[l<32]=v[l+32], r.y[l>=32]=v[l].
  // xor32 result: lanes<32 need v[l+32] (r.y), lanes>=32 need v[l-32] (r.x).
  i32x2 r = __builtin_amdgcn_permlane32_swap(
      __builtin_bit_cast(int, v), __builtin_bit_cast(int, v), false, false);
  return __builtin_bit_cast(float, hi ? r.x : r.y);
}

template<int MASK>
static __device__ __forceinline__ float lxor(float v, bool hi32) {
  if constexpr (MASK == 1)       return dppf<0xB1>(v);
  else if constexpr (MASK == 2)  return dppf<0x4E>(v);
  else if constexpr (MASK == 3)  return dppf<0x1B>(v);
  else if constexpr (MASK == 4)  return dppf<0x1B>(dppf<0x141>(v));   // 7^3
  else if constexpr (MASK == 6)  return dppf<0xB1>(dppf<0x141>(v));   // 7^1
  else if constexpr (MASK == 8)  return dppf<0x128>(v);
  else if constexpr (MASK == 12) return swzf<0x301F>(v);
  else if constexpr (MASK == 16) return swzf<0x401F>(v);
  else if constexpr (MASK == 24) return swzf<0x401F>(dppf<0x128>(v));
  else if constexpr (MASK == 32) return pswap32(v, hi32);
  else if constexpr (MASK == 48) return swzf<0x401F>(pswap32(v, hi32));
  else return __shfl_xor(v, MASK, 64);
}
template<int MASK>
static __device__ __forceinline__ f32x2 lxor2(f32x2 v, bool hi32) {
  f32x2 r; r.x = lxor<MASK>(v.x, hi32); r.y = lxor<MASK>(v.y, hi32); return r;
}
// group-uniform broadcast from lane SRC (valid after full 64-lane reduce)
template<int SRC>
static __device__ __forceinline__ f32x2 bswz2(f32x2 v) {
  f32x2 r; r.x = swzf<(SRC<<5)>(v.x); r.y = swzf<(SRC<<5)>(v.y); return r;
}
static __device__ __forceinline__ f32x2 xorsgn2(f32x2 v, int sgn) {
  i32x2 iv = __builtin_bit_cast(i32x2, v);
  iv.x ^= sgn; iv.y ^= sgn;
  return __builtin_bit_cast(f32x2, iv);
}

// ---------------------------------------------------------------------------
// Index algebra identical to R2/R3 (verified): amplitude p = lane*4 + r,
// wires 0..5 = lane bits 5..0, wires 6,7 = r bits 1,0. CNOTs absorbed into
// gate masks via GF(2) relabeling (A1/A2).
// Rot structure: u11 = conj(u00), u10 = -conj(u01) =>
//   A = (Ar, ±Ai), B = (±Br, Bi) with sign = (-1)^(pl^rp); pl-sign via xor,
//   rp-sign via compile-time pkfma/pkfman selection.
// ---------------------------------------------------------------------------
template<int R, int LMASK, int RMASK, int HIR>
static __device__ __forceinline__ void gate_step(
    const f32x2 ar[4], const f32x2 ai[4], f32x2& nr, f32x2& ni,
    f32x2 Ar, f32x2 AiS, f32x2 BrS, f32x2 Bi, bool hi32)
{
  constexpr int  rx = R & HIR;
  constexpr bool RP = (rx == 1 || rx == 2);   // parity of 2-bit value
  const f32x2 sr = ar[R], si = ai[R];
  f32x2 pr, pi;
  if constexpr (LMASK != 0) {
    pr = lxor2<LMASK>(ar[R ^ RMASK], hi32);
    pi = lxor2<LMASK>(ai[R ^ RMASK], hi32);
  } else {
    pr = ar[R ^ RMASK]; pi = ai[R ^ RMASK];
  }
  // nr = Ar*sr - (±AiS)*si + (±BrS)*pr - Bi*pi
  f32x2 t = pkmul(Ar, sr);
  t = pkfma_s<!RP>(AiS, si, t);
  t = pkfma_s< RP>(BrS, pr, t);
  t = pkfman(Bi, pi, t);
  nr = t;
  // ni = Ar*si + (±AiS)*sr + (±BrS)*pi + Bi*pr
  t = pkmul(Ar, si);
  t = pkfma_s< RP>(AiS, sr, t);
  t = pkfma_s< RP>(BrS, pi, t);
  t = pkfma(Bi, pr, t);
  ni = t;
}

template<int LMASK, int RMASK, int HIL, int HIR>
static __device__ __forceinline__ void applyG2(f32x2 ar[4], f32x2 ai[4],
    const f32x4* __restrict__ g4, int lane, bool hi32)
{
  const f32x4 ga = g4[0];  // u00r,u00r,u00i,u00i
  const f32x4 gb = g4[1];  // u01r,u01r,u01i,u01i
  const f32x2 Ar = __builtin_shufflevector(ga, ga, 0, 1);
  f32x2 AiS      = __builtin_shufflevector(ga, ga, 2, 3);
  f32x2 BrS      = __builtin_shufflevector(gb, gb, 0, 1);
  const f32x2 Bi = __builtin_shufflevector(gb, gb, 2, 3);
  if constexpr (HIL != 0) {
    const int sgn = ((__popc(lane & HIL) & 1) != 0) ? (int)0x80000000 : 0;
    AiS = xorsgn2(AiS, sgn);
    BrS = xorsgn2(BrS, sgn);
  }
  f32x2 nr[4], ni[4];
  gate_step<0, LMASK, RMASK, HIR>(ar, ai, nr[0], ni[0], Ar, AiS, BrS, Bi, hi32);
  gate_step<1, LMASK, RMASK, HIR>(ar, ai, nr[1], ni[1], Ar, AiS, BrS, Bi, hi32);
  gate_step<2, LMASK, RMASK, HIR>(ar, ai, nr[2], ni[2], Ar, AiS, BrS, Bi, hi32);
  gate_step<3, LMASK, RMASK, HIR>(ar, ai, nr[3], ni[3], Ar, AiS, BrS, Bi, hi32);
#pragma unroll
  for (int r = 0; r < 4; ++r) { ar[r] = nr[r]; ai[r] = ni[r]; }
}

// ---------------------------------------------------------------------------
// Setup: 16 Rot gates -> 8 floats each: u00r,u00r,u00i,u00i,u01r,u01r,u01i,u01i
// ---------------------------------------------------------------------------
__global__ void qbranch_setup(const float* __restrict__ weights,
                              float* __restrict__ gates)
{
  int t = threadIdx.x;
  if (t >= 16) return;
  float phi = weights[t*3 + 0];
  float th  = weights[t*3 + 1];
  float om  = weights[t*3 + 2];
  float ct = cosf(th * 0.5f), st = sinf(th * 0.5f);
  float ap = (phi + om) * 0.5f, am = (phi - om) * 0.5f;
  float u00r =  cosf(ap)*ct, u00i = -sinf(ap)*ct;
  float u01r = -cosf(am)*st, u01i = -sinf(am)*st;
  float* g = gates + t*8;
  g[0]=u00r; g[1]=u00r; g[2]=u00i; g[3]=u00i;
  g[4]=u01r; g[5]=u01r; g[6]=u01i; g[7]=u01i;
}

// ---------------------------------------------------------------------------
// Main: 4 waves/block, TWO batch elements per wave (lo/hi of f32x2).
// ---------------------------------------------------------------------------
__global__ __launch_bounds__(256) void qbranch_main(
    const float* __restrict__ x,     // (B,8)
    const float* __restrict__ gates, // 16 gates x 8 floats
    const float* __restrict__ Wm,    // (8,64)
    const float* __restrict__ bias,  // (64)
    const float* __restrict__ gamma, // (64)
    const float* __restrict__ beta,  // (64)
    float* __restrict__ out,         // (B,64)
    int B)
{
  const int lane = threadIdx.x & 63;
  const int wid  = threadIdx.x >> 6;
  const int bA   = blockIdx.x * 8 + wid * 2;
  const int bB   = bA + 1;
  if (bA >= B) return;
  const int bBl  = (bB < B) ? bB : bA;
  const bool hi32 = lane >= 32;

  // --- trig: lanes 0..15 elem A (2w: cos, 2w+1: sin), 16..31 elem B --------
  float val = 0.f;
  if (lane < 32) {
    const int e = lane >> 4;
    const int t = lane & 15;
    float xv = x[(e ? bBl : bA)*8 + (t >> 1)];
    float th = 1.f - 2.f / (__expf(2.f*xv) + 1.f);   // tanh
    float ha = th * (PI_F * 0.5f);
    val = (t & 1) ? __sinf(ha) : __cosf(ha);
  }

  const int l5=(lane>>5)&1, l4=(lane>>4)&1, l3=(lane>>3)&1,
            l2=(lane>>2)&1, l1=(lane>>1)&1, l0=lane&1;
  float m0A=__shfl(val, 0+l5,64), m0B=__shfl(val,16+ 0+l5,64);
  float m1A=__shfl(val, 2+l4,64), m1B=__shfl(val,16+ 2+l4,64);
  float m2A=__shfl(val, 4+l3,64), m2B=__shfl(val,16+ 4+l3,64);
  float m3A=__shfl(val, 6+l2,64), m3B=__shfl(val,16+ 6+l2,64);
  float m4A=__shfl(val, 8+l1,64), m4B=__shfl(val,16+ 8+l1,64);
  float m5A=__shfl(val,10+l0,64), m5B=__shfl(val,16+10+l0,64);
  float c6A=__shfl(val,12,64), s6A=__shfl(val,13,64);
  float c7A=__shfl(val,14,64), s7A=__shfl(val,15,64);
  float c6B=__shfl(val,28,64), s6B=__shfl(val,29,64);
  float c7B=__shfl(val,30,64), s7B=__shfl(val,31,64);

  const float pA = m0A*m1A*m2A*m3A*m4A*m5A;
  const float pB = m0B*m1B*m2B*m3B*m4B*m5B;
  f32x2 mag[4];
  mag[0].x = pA*c6A*c7A;  mag[0].y = pB*c6B*c7B;
  mag[1].x = pA*c6A*s7A;  mag[1].y = pB*c6B*s7B;
  mag[2].x = pA*s6A*c7A;  mag[2].y = pB*s6B*c7B;
  mag[3].x = pA*s6A*s7A;  mag[3].y = pB*s6B*s7B;

  // product state: amp(p) = mag(p) * (-i)^popc(p)
  f32x2 ar[4], ai[4];
  {
    const int kl = __popc(lane);
    const f32x2 zero = {0.f, 0.f};
#pragma unroll
    for (int r = 0; r < 4; ++r) {
      const int k = kl + ((r >> 1) & 1) + (r & 1);
      f32x2 sgn = (k & 2) ? -mag[r] : mag[r];
      ar[r] = (k & 1) ? zero : sgn;
      ai[r] = (k & 1) ? -sgn : zero;
    }
  }

  const f32x4* G = (const f32x4*)gates;

  // --- layer 0 Rot gates (A = I) ------------------------------------------
  applyG2<0x20, 0, 0x20, 0>(ar, ai, G +  0*2, lane, hi32);
  applyG2<0x10, 0, 0x10, 0>(ar, ai, G +  1*2, lane, hi32);
  applyG2<0x08, 0, 0x08, 0>(ar, ai, G +  2*2, lane, hi32);
  applyG2<0x04, 0, 0x04, 0>(ar, ai, G +  3*2, lane, hi32);
  applyG2<0x02, 0, 0x02, 0>(ar, ai, G +  4*2, lane, hi32);
  applyG2<0x01, 0, 0x01, 0>(ar, ai, G +  5*2, lane, hi32);
  applyG2<0x00, 2, 0x00, 2>(ar, ai, G +  6*2, lane, hi32);
  applyG2<0x00, 1, 0x00, 1>(ar, ai, G +  7*2, lane, hi32);

  // --- layer 1 Rot gates (CNOT ring r=1 absorbed) -------------------------
  applyG2<0x30, 0, 0x1F, 3>(ar, ai, G +  8*2, lane, hi32);
  applyG2<0x18, 0, 0x30, 0>(ar, ai, G +  9*2, lane, hi32);
  applyG2<0x0C, 0, 0x38, 0>(ar, ai, G + 10*2, lane, hi32);
  applyG2<0x06, 0, 0x3C, 0>(ar, ai, G + 11*2, lane, hi32);
  applyG2<0x03, 0, 0x3E, 0>(ar, ai, G + 12*2, lane, hi32);
  applyG2<0x01, 2, 0x3F, 0>(ar, ai, G + 13*2, lane, hi32);
  applyG2<0x00, 3, 0x3F, 2>(ar, ai, G + 14*2, lane, hi32);
  applyG2<0x30, 1, 0x3F, 3>(ar, ai, G + 15*2, lane, hi32);

  // --- Z expectations with A2 sign masks ----------------------------------
  f32x2 pp0 = pkfma(ar[0], ar[0], pkmul(ai[0], ai[0]));
  f32x2 pp1 = pkfma(ar[1], ar[1], pkmul(ai[1], ai[1]));
  f32x2 pp2 = pkfma(ar[2], ar[2], pkmul(ai[2], ai[2]));
  f32x2 pp3 = pkfma(ar[3], ar[3], pkmul(ai[3], ai[3]));
  f32x2 s01 = pkadd(pp0, pp1), d01 = pksub(pp0, pp1);
  f32x2 s23 = pkadd(pp2, pp3), d23 = pksub(pp2, pp3);
  f32x2 q0 = pkadd(s01, s23);
  f32x2 q1 = pkadd(d01, d23);
  f32x2 q2 = pksub(s01, s23);
  f32x2 q3 = pksub(d01, d23);
  f32x2 n0 = -q0, n1 = -q1, n2 = -q2, n3 = -q3;

  f32x2 zp[8];
  zp[0] = (__popc(lane & 0x39) & 1) ? n2 : q2;
  zp[1] = (__popc(lane & 0x3C) & 1) ? n3 : q3;
  zp[2] = (__popc(lane & 0x27) & 1) ? n3 : q3;
  zp[3] = (__popc(lane & 0x0C) & 1) ? n0 : q0;
  zp[4] = (__popc(lane & 0x19) & 1) ? n3 : q3;
  zp[5] = (__popc(lane & 0x33) & 1) ? n0 : q0;
  zp[6] = (__popc(lane & 0x26) & 1) ? n1 : q1;
  zp[7] = (__popc(lane & 0x0C) & 1) ? n3 : q3;

  // --- split-butterfly reduce: lane ends with z_{4*b0+2*b1+b2} ------------
  const bool lb0 = (lane & 1) != 0, lb1 = (lane & 2) != 0, lb2 = (lane & 4) != 0;
  f32x2 u[4];
#pragma unroll
  for (int k = 0; k < 4; ++k) {
    f32x2 snd = lb0 ? zp[k] : zp[k+4];
    f32x2 rcv = lxor2<1>(snd, hi32);
    u[k] = pkadd(lb0 ? zp[k+4] : zp[k], rcv);
  }
  f32x2 v2[2];
#pragma unroll
  for (int k = 0; k < 2; ++k) {
    f32x2 snd = lb1 ? u[k] : u[k+2];
    f32x2 rcv = lxor2<2>(snd, hi32);
    v2[k] = pkadd(lb1 ? u[k+2] : u[k], rcv);
  }
  f32x2 snd3 = lb2 ? v2[0] : v2[1];
  f32x2 zs = pkadd(lb2 ? v2[1] : v2[0], lxor2<4>(snd3, hi32));
  zs = pkadd(zs, lxor2< 8>(zs, hi32));
  zs = pkadd(zs, lxor2<16>(zs, hi32));
  zs = pkadd(zs, lxor2<32>(zs, hi32));

  const f32x2 z0 = bswz2<0>(zs);
  const f32x2 z1 = bswz2<4>(zs);
  const f32x2 z2 = bswz2<2>(zs);
  const f32x2 z3 = bswz2<6>(zs);
  const f32x2 z4 = bswz2<1>(zs);
  const f32x2 z5 = bswz2<5>(zs);
  const f32x2 z6 = bswz2<3>(zs);
  const f32x2 z7 = bswz2<7>(zs);

  // --- projection (8 -> 64), lane j computes h[j] for both elements -------
  const int j = lane;
  f32x2 h = dup2(bias[j]);
  h = pkfma(dup2(Wm[0*64 + j]), z0, h);
  h = pkfma(dup2(Wm[1*64 + j]), z1, h);
  h = pkfma(dup2(Wm[2*64 + j]), z2, h);
  h = pkfma(dup2(Wm[3*64 + j]), z3, h);
  h = pkfma(dup2(Wm[4*64 + j]), z4, h);
  h = pkfma(dup2(Wm[5*64 + j]), z5, h);
  h = pkfma(dup2(Wm[6*64 + j]), z6, h);
  h = pkfma(dup2(Wm[7*64 + j]), z7, h);

  // --- LayerNorm: fused sum/sumsq butterfly -------------------------------
  f32x2 S = h, Q = pkmul(h, h);
  f32x2 snd4 = lb0 ? S : Q;
  f32x2 acc = pkadd(lb0 ? Q : S, lxor2<1>(snd4, hi32));
  acc = pkadd(acc, lxor2< 2>(acc, hi32));
  acc = pkadd(acc, lxor2< 4>(acc, hi32));
  acc = pkadd(acc, lxor2< 8>(acc, hi32));
  acc = pkadd(acc, lxor2<16>(acc, hi32));
  acc = pkadd(acc, lxor2<32>(acc, hi32));
  const f32x2 Ssum = bswz2<0>(acc);
  const f32x2 Qsum = bswz2<1>(acc);
  const f32x2 inv64 = dup2(1.f/64.f);
  f32x2 mu  = pkmul(Ssum, inv64);
  f32x2 var = pkfman(mu, mu, pkmul(Qsum, inv64));
  f32x2 d   = pksub(h, mu);
  f32x2 rs;
  rs.x = rsqrtf(var.x + 1e-5f);
  rs.y = rsqrtf(var.y + 1e-5f);
  f32x2 o = pkfma(pkmul(dup2(gamma[j]), d), rs, dup2(beta[j]));

  out[bA*64 + j] = o.x;
  if (bB < B) out[bB*64 + j] = o.y;
}

// ---------------------------------------------------------------------------
extern "C" void kernel_launch(void* const* d_in, const int* in_sizes, int n_in,
                              void* d_out, int out_size, void* d_ws, size_t ws_size,
                              hipStream_t stream)
{
  const float* x       = (const float*)d_in[0];
  const float* weights = (const float*)d_in[1];
  const float* Wm      = (const float*)d_in[2];
  const float* bias    = (const float*)d_in[3];
  const float* gamma   = (const float*)d_in[4];
  const float* beta    = (const float*)d_in[5];
  float* out   = (float*)d_out;
  float* gates = (float*)d_ws;   // 16 gates * 8 floats

  const int B = in_sizes[0] / 8;

  hipLaunchKernelGGL(qbranch_setup, dim3(1), dim3(64), 0, stream, weights, gates);
  hipLaunchKernelGGL(qbranch_main, dim3((B + 7) / 8), dim3(256), 0, stream,
                     x, gates, Wm, bias, gamma, beta, out, B);
}

// Round 6
// 31.491 us; speedup vs baseline: 1.1727x; 1.0365x over previous
//
#include <hip/hip_runtime.h>
#include <math.h>

#define PI_F 3.14159265358979323846f

typedef float f32x2 __attribute__((ext_vector_type(2)));
typedef float f32x4 __attribute__((ext_vector_type(4)));
typedef int   i32x2 __attribute__((ext_vector_type(2)));

// ---------------------------------------------------------------------------
// Packed-FP32 helpers — PLAIN C++ vector ops (no inline asm; let LLVM pick
// v_pk_* or dual scalar v_fma; avoids asm operand-constraint mov storms).
// ---------------------------------------------------------------------------
static __device__ __forceinline__ f32x2 pkmul(f32x2 a, f32x2 b)            { return a * b; }
static __device__ __forceinline__ f32x2 pkadd(f32x2 a, f32x2 b)            { return a + b; }
static __device__ __forceinline__ f32x2 pksub(f32x2 a, f32x2 b)            { return a - b; }
static __device__ __forceinline__ f32x2 pkfma(f32x2 a, f32x2 b, f32x2 c)   { return a * b + c; }
static __device__ __forceinline__ f32x2 pkfman(f32x2 a, f32x2 b, f32x2 c)  { return c - a * b; }
template<bool NEG>
static __device__ __forceinline__ f32x2 pkfma_s(f32x2 a, f32x2 b, f32x2 c) {
  if constexpr (NEG) return c - a * b; else return a * b + c;
}
static __device__ __forceinline__ f32x2 dup2(float s) { f32x2 r; r.x = s; r.y = s; return r; }

// ---------------------------------------------------------------------------
// Cross-lane exchange primitives (hardware-verified in R5).
// dpp ctrl: quad_perm[1,0,3,2]=0xB1 (xor1), [2,3,0,1]=0x4E (xor2),
//           [3,2,1,0]=0x1B (xor3), row_half_mirror=0x141 (xor7),
//           row_ror:8=0x128 (xor8).
// ds_swizzle BitMode offset = (xor<<10)|(or<<5)|and.
// ---------------------------------------------------------------------------
template<int CTRL>
static __device__ __forceinline__ float dppf(float v) {
  return __builtin_bit_cast(float,
    __builtin_amdgcn_update_dpp(0, __builtin_bit_cast(int, v), CTRL, 0xF, 0xF, false));
}
template<int OFF>
static __device__ __forceinline__ float swzf(float v) {
  return __builtin_bit_cast(float,
    __builtin_amdgcn_ds_swizzle(__builtin_bit_cast(int, v), OFF));
}
static __device__ __forceinline__ float pswap32(float v, bool hi) {
  // v_permlane32_swap_b32 vdst,vsrc swaps vdst.hi32 <-> vsrc.lo32.
  // With both = v: r.x[l>=32]=v[l-32]; r.y[l<32]=v[l+32].
  // xor32: lanes<32 take r.y, lanes>=32 take r.x.   (verified R5)
  i32x2 r = __builtin_amdgcn_permlane32_swap(
      __builtin_bit_cast(int, v), __builtin_bit_cast(int, v), false, false);
  return __builtin_bit_cast(float, hi ? r.x : r.y);
}

template<int MASK>
static __device__ __forceinline__ float lxor(float v, bool hi32) {
  if constexpr (MASK == 1)       return dppf<0xB1>(v);
  else if constexpr (MASK == 2)  return dppf<0x4E>(v);
  else if constexpr (MASK == 3)  return dppf<0x1B>(v);
  else if constexpr (MASK == 4)  return dppf<0x1B>(dppf<0x141>(v));   // 7^3
  else if constexpr (MASK == 6)  return dppf<0xB1>(dppf<0x141>(v));   // 7^1
  else if constexpr (MASK == 8)  return dppf<0x128>(v);
  else if constexpr (MASK == 12) return swzf<0x301F>(v);
  else if constexpr (MASK == 16) return swzf<0x401F>(v);
  else if constexpr (MASK == 24) return swzf<0x401F>(dppf<0x128>(v));
  else if constexpr (MASK == 32) return pswap32(v, hi32);
  else if constexpr (MASK == 48) return swzf<0x401F>(pswap32(v, hi32));
  else return __shfl_xor(v, MASK, 64);
}
template<int MASK>
static __device__ __forceinline__ f32x2 lxor2(f32x2 v, bool hi32) {
  f32x2 r; r.x = lxor<MASK>(v.x, hi32); r.y = lxor<MASK>(v.y, hi32); return r;
}
// group-uniform broadcast from lane SRC (valid after full 64-lane reduce)
template<int SRC>
static __device__ __forceinline__ f32x2 bswz2(f32x2 v) {
  f32x2 r; r.x = swzf<(SRC<<5)>(v.x); r.y = swzf<(SRC<<5)>(v.y); return r;
}
static __device__ __forceinline__ f32x2 xorsgn2(f32x2 v, int sgn) {
  i32x2 iv = __builtin_bit_cast(i32x2, v);
  iv.x ^= sgn; iv.y ^= sgn;
  return __builtin_bit_cast(f32x2, iv);
}

// ---------------------------------------------------------------------------
// Index algebra identical to R2..R5 (verified): amplitude p = lane*4 + r,
// wires 0..5 = lane bits 5..0, wires 6,7 = r bits 1,0. CNOTs absorbed into
// gate masks via GF(2) relabeling (A1/A2).
// Rot structure: u11 = conj(u00), u10 = -conj(u01) =>
//   A = (Ar, ±Ai), B = (±Br, Bi) with sign = (-1)^(pl^rp); pl-sign via xor,
//   rp-sign via compile-time fma/fman selection.
// ---------------------------------------------------------------------------
template<int R, int LMASK, int RMASK, int HIR>
static __device__ __forceinline__ void gate_step(
    const f32x2 ar[4], const f32x2 ai[4], f32x2& nr, f32x2& ni,
    f32x2 Ar, f32x2 AiS, f32x2 BrS, f32x2 Bi, bool hi32)
{
  constexpr int  rx = R & HIR;
  constexpr bool RP = (rx == 1 || rx == 2);   // parity of 2-bit value
  const f32x2 sr = ar[R], si = ai[R];
  f32x2 pr, pi;
  if constexpr (LMASK != 0) {
    pr = lxor2<LMASK>(ar[R ^ RMASK], hi32);
    pi = lxor2<LMASK>(ai[R ^ RMASK], hi32);
  } else {
    pr = ar[R ^ RMASK]; pi = ai[R ^ RMASK];
  }
  // nr = Ar*sr - (±AiS)*si + (±BrS)*pr - Bi*pi
  f32x2 t = pkmul(Ar, sr);
  t = pkfma_s<!RP>(AiS, si, t);
  t = pkfma_s< RP>(BrS, pr, t);
  t = pkfman(Bi, pi, t);
  nr = t;
  // ni = Ar*si + (±AiS)*sr + (±BrS)*pi + Bi*pr
  t = pkmul(Ar, si);
  t = pkfma_s< RP>(AiS, sr, t);
  t = pkfma_s< RP>(BrS, pi, t);
  t = pkfma(Bi, pr, t);
  ni = t;
}

template<int LMASK, int RMASK, int HIL, int HIR>
static __device__ __forceinline__ void applyG2(f32x2 ar[4], f32x2 ai[4],
    const f32x4* __restrict__ g4, int lane, bool hi32)
{
  const f32x4 ga = g4[0];  // u00r,u00r,u00i,u00i
  const f32x4 gb = g4[1];  // u01r,u01r,u01i,u01i
  const f32x2 Ar = __builtin_shufflevector(ga, ga, 0, 1);
  f32x2 AiS      = __builtin_shufflevector(ga, ga, 2, 3);
  f32x2 BrS      = __builtin_shufflevector(gb, gb, 0, 1);
  const f32x2 Bi = __builtin_shufflevector(gb, gb, 2, 3);
  if constexpr (HIL != 0) {
    const int sgn = ((__popc(lane & HIL) & 1) != 0) ? (int)0x80000000 : 0;
    AiS = xorsgn2(AiS, sgn);
    BrS = xorsgn2(BrS, sgn);
  }
  f32x2 nr[4], ni[4];
  gate_step<0, LMASK, RMASK, HIR>(ar, ai, nr[0], ni[0], Ar, AiS, BrS, Bi, hi32);
  gate_step<1, LMASK, RMASK, HIR>(ar, ai, nr[1], ni[1], Ar, AiS, BrS, Bi, hi32);
  gate_step<2, LMASK, RMASK, HIR>(ar, ai, nr[2], ni[2], Ar, AiS, BrS, Bi, hi32);
  gate_step<3, LMASK, RMASK, HIR>(ar, ai, nr[3], ni[3], Ar, AiS, BrS, Bi, hi32);
#pragma unroll
  for (int r = 0; r < 4; ++r) { ar[r] = nr[r]; ai[r] = ni[r]; }
}

// ---------------------------------------------------------------------------
// Setup: 16 Rot gates -> 8 floats each: u00r,u00r,u00i,u00i,u01r,u01r,u01i,u01i
// ---------------------------------------------------------------------------
__global__ void qbranch_setup(const float* __restrict__ weights,
                              float* __restrict__ gates)
{
  int t = threadIdx.x;
  if (t >= 16) return;
  float phi = weights[t*3 + 0];
  float th  = weights[t*3 + 1];
  float om  = weights[t*3 + 2];
  float ct = cosf(th * 0.5f), st = sinf(th * 0.5f);
  float ap = (phi + om) * 0.5f, am = (phi - om) * 0.5f;
  float u00r =  cosf(ap)*ct, u00i = -sinf(ap)*ct;
  float u01r = -cosf(am)*st, u01i = -sinf(am)*st;
  float* g = gates + t*8;
  g[0]=u00r; g[1]=u00r; g[2]=u00i; g[3]=u00i;
  g[4]=u01r; g[5]=u01r; g[6]=u01i; g[7]=u01i;
}

// ---------------------------------------------------------------------------
// Main: 4 waves/block, TWO batch elements per wave (lo/hi of f32x2).
// ---------------------------------------------------------------------------
__global__ __launch_bounds__(256) void qbranch_main(
    const float* __restrict__ x,     // (B,8)
    const float* __restrict__ gates, // 16 gates x 8 floats
    const float* __restrict__ Wm,    // (8,64)
    const float* __restrict__ bias,  // (64)
    const float* __restrict__ gamma, // (64)
    const float* __restrict__ beta,  // (64)
    float* __restrict__ out,         // (B,64)
    int B)
{
  const int lane = threadIdx.x & 63;
  const int wid  = threadIdx.x >> 6;
  const int bA   = blockIdx.x * 8 + wid * 2;
  const int bB   = bA + 1;
  if (bA >= B) return;
  const int bBl  = (bB < B) ? bB : bA;
  const bool hi32 = lane >= 32;

  // --- trig: lanes 0..15 elem A (2w: cos, 2w+1: sin), 16..31 elem B --------
  float val = 0.f;
  if (lane < 32) {
    const int e = lane >> 4;
    const int t = lane & 15;
    float xv = x[(e ? bBl : bA)*8 + (t >> 1)];
    float th = 1.f - 2.f / (__expf(2.f*xv) + 1.f);   // tanh
    float ha = th * (PI_F * 0.5f);
    val = (t & 1) ? __sinf(ha) : __cosf(ha);
  }

  const int l5=(lane>>5)&1, l4=(lane>>4)&1, l3=(lane>>3)&1,
            l2=(lane>>2)&1, l1=(lane>>1)&1, l0=lane&1;
  float m0A=__shfl(val, 0+l5,64), m0B=__shfl(val,16+ 0+l5,64);
  float m1A=__shfl(val, 2+l4,64), m1B=__shfl(val,16+ 2+l4,64);
  float m2A=__shfl(val, 4+l3,64), m2B=__shfl(val,16+ 4+l3,64);
  float m3A=__shfl(val, 6+l2,64), m3B=__shfl(val,16+ 6+l2,64);
  float m4A=__shfl(val, 8+l1,64), m4B=__shfl(val,16+ 8+l1,64);
  float m5A=__shfl(val,10+l0,64), m5B=__shfl(val,16+10+l0,64);
  float c6A=__shfl(val,12,64), s6A=__shfl(val,13,64);
  float c7A=__shfl(val,14,64), s7A=__shfl(val,15,64);
  float c6B=__shfl(val,28,64), s6B=__shfl(val,29,64);
  float c7B=__shfl(val,30,64), s7B=__shfl(val,31,64);

  const float pA = m0A*m1A*m2A*m3A*m4A*m5A;
  const float pB = m0B*m1B*m2B*m3B*m4B*m5B;
  f32x2 mag[4];
  mag[0].x = pA*c6A*c7A;  mag[0].y = pB*c6B*c7B;
  mag[1].x = pA*c6A*s7A;  mag[1].y = pB*c6B*s7B;
  mag[2].x = pA*s6A*c7A;  mag[2].y = pB*s6B*c7B;
  mag[3].x = pA*s6A*s7A;  mag[3].y = pB*s6B*s7B;

  // product state: amp(p) = mag(p) * (-i)^popc(p)
  f32x2 ar[4], ai[4];
  {
    const int kl = __popc(lane);
    const f32x2 zero = {0.f, 0.f};
#pragma unroll
    for (int r = 0; r < 4; ++r) {
      const int k = kl + ((r >> 1) & 1) + (r & 1);
      f32x2 sgn = (k & 2) ? -mag[r] : mag[r];
      ar[r] = (k & 1) ? zero : sgn;
      ai[r] = (k & 1) ? -sgn : zero;
    }
  }

  const f32x4* G = (const f32x4*)gates;

  // --- layer 0 Rot gates (A = I) ------------------------------------------
  applyG2<0x20, 0, 0x20, 0>(ar, ai, G +  0*2, lane, hi32);
  applyG2<0x10, 0, 0x10, 0>(ar, ai, G +  1*2, lane, hi32);
  applyG2<0x08, 0, 0x08, 0>(ar, ai, G +  2*2, lane, hi32);
  applyG2<0x04, 0, 0x04, 0>(ar, ai, G +  3*2, lane, hi32);
  applyG2<0x02, 0, 0x02, 0>(ar, ai, G +  4*2, lane, hi32);
  applyG2<0x01, 0, 0x01, 0>(ar, ai, G +  5*2, lane, hi32);
  applyG2<0x00, 2, 0x00, 2>(ar, ai, G +  6*2, lane, hi32);
  applyG2<0x00, 1, 0x00, 1>(ar, ai, G +  7*2, lane, hi32);

  // --- layer 1 Rot gates (CNOT ring r=1 absorbed) -------------------------
  applyG2<0x30, 0, 0x1F, 3>(ar, ai, G +  8*2, lane, hi32);
  applyG2<0x18, 0, 0x30, 0>(ar, ai, G +  9*2, lane, hi32);
  applyG2<0x0C, 0, 0x38, 0>(ar, ai, G + 10*2, lane, hi32);
  applyG2<0x06, 0, 0x3C, 0>(ar, ai, G + 11*2, lane, hi32);
  applyG2<0x03, 0, 0x3E, 0>(ar, ai, G + 12*2, lane, hi32);
  applyG2<0x01, 2, 0x3F, 0>(ar, ai, G + 13*2, lane, hi32);
  applyG2<0x00, 3, 0x3F, 2>(ar, ai, G + 14*2, lane, hi32);
  applyG2<0x30, 1, 0x3F, 3>(ar, ai, G + 15*2, lane, hi32);

  // --- Z expectations with A2 sign masks ----------------------------------
  f32x2 pp0 = pkfma(ar[0], ar[0], pkmul(ai[0], ai[0]));
  f32x2 pp1 = pkfma(ar[1], ar[1], pkmul(ai[1], ai[1]));
  f32x2 pp2 = pkfma(ar[2], ar[2], pkmul(ai[2], ai[2]));
  f32x2 pp3 = pkfma(ar[3], ar[3], pkmul(ai[3], ai[3]));
  f32x2 s01 = pkadd(pp0, pp1), d01 = pksub(pp0, pp1);
  f32x2 s23 = pkadd(pp2, pp3), d23 = pksub(pp2, pp3);
  f32x2 q0 = pkadd(s01, s23);
  f32x2 q1 = pkadd(d01, d23);
  f32x2 q2 = pksub(s01, s23);
  f32x2 q3 = pksub(d01, d23);
  f32x2 n0 = -q0, n1 = -q1, n2 = -q2, n3 = -q3;

  f32x2 zp[8];
  zp[0] = (__popc(lane & 0x39) & 1) ? n2 : q2;
  zp[1] = (__popc(lane & 0x3C) & 1) ? n3 : q3;
  zp[2] = (__popc(lane & 0x27) & 1) ? n3 : q3;
  zp[3] = (__popc(lane & 0x0C) & 1) ? n0 : q0;
  zp[4] = (__popc(lane & 0x19) & 1) ? n3 : q3;
  zp[5] = (__popc(lane & 0x33) & 1) ? n0 : q0;
  zp[6] = (__popc(lane & 0x26) & 1) ? n1 : q1;
  zp[7] = (__popc(lane & 0x0C) & 1) ? n3 : q3;

  // --- split-butterfly reduce: lane ends with z_{4*b0+2*b1+b2} ------------
  const bool lb0 = (lane & 1) != 0, lb1 = (lane & 2) != 0, lb2 = (lane & 4) != 0;
  f32x2 u[4];
#pragma unroll
  for (int k = 0; k < 4; ++k) {
    f32x2 snd = lb0 ? zp[k] : zp[k+4];
    f32x2 rcv = lxor2<1>(snd, hi32);
    u[k] = pkadd(lb0 ? zp[k+4] : zp[k], rcv);
  }
  f32x2 v2[2];
#pragma unroll
  for (int k = 0; k < 2; ++k) {
    f32x2 snd = lb1 ? u[k] : u[k+2];
    f32x2 rcv = lxor2<2>(snd, hi32);
    v2[k] = pkadd(lb1 ? u[k+2] : u[k], rcv);
  }
  f32x2 snd3 = lb2 ? v2[0] : v2[1];
  f32x2 zs = pkadd(lb2 ? v2[1] : v2[0], lxor2<4>(snd3, hi32));
  zs = pkadd(zs, lxor2< 8>(zs, hi32));
  zs = pkadd(zs, lxor2<16>(zs, hi32));
  zs = pkadd(zs, lxor2<32>(zs, hi32));

  const f32x2 z0 = bswz2<0>(zs);
  const f32x2 z1 = bswz2<4>(zs);
  const f32x2 z2 = bswz2<2>(zs);
  const f32x2 z3 = bswz2<6>(zs);
  const f32x2 z4 = bswz2<1>(zs);
  const f32x2 z5 = bswz2<5>(zs);
  const f32x2 z6 = bswz2<3>(zs);
  const f32x2 z7 = bswz2<7>(zs);

  // --- projection (8 -> 64), lane j computes h[j] for both elements -------
  const int j = lane;
  f32x2 h = dup2(bias[j]);
  h = pkfma(dup2(Wm[0*64 + j]), z0, h);
  h = pkfma(dup2(Wm[1*64 + j]), z1, h);
  h = pkfma(dup2(Wm[2*64 + j]), z2, h);
  h = pkfma(dup2(Wm[3*64 + j]), z3, h);
  h = pkfma(dup2(Wm[4*64 + j]), z4, h);
  h = pkfma(dup2(Wm[5*64 + j]), z5, h);
  h = pkfma(dup2(Wm[6*64 + j]), z6, h);
  h = pkfma(dup2(Wm[7*64 + j]), z7, h);

  // --- LayerNorm: fused sum/sumsq butterfly -------------------------------
  f32x2 S = h, Q = pkmul(h, h);
  f32x2 snd4 = lb0 ? S : Q;
  f32x2 acc = pkadd(lb0 ? Q : S, lxor2<1>(snd4, hi32));
  acc = pkadd(acc, lxor2< 2>(acc, hi32));
  acc = pkadd(acc, lxor2< 4>(acc, hi32));
  acc = pkadd(acc, lxor2< 8>(acc, hi32));
  acc = pkadd(acc, lxor2<16>(acc, hi32));
  acc = pkadd(acc, lxor2<32>(acc, hi32));
  const f32x2 Ssum = bswz2<0>(acc);
  const f32x2 Qsum = bswz2<1>(acc);
  const f32x2 inv64 = dup2(1.f/64.f);
  f32x2 mu  = pkmul(Ssum, inv64);
  f32x2 var = pkfman(mu, mu, pkmul(Qsum, inv64));
  f32x2 d   = pksub(h, mu);
  f32x2 rs;
  rs.x = rsqrtf(var.x + 1e-5f);
  rs.y = rsqrtf(var.y + 1e-5f);
  f32x2 o = pkfma(pkmul(dup2(gamma[j]), d), rs, dup2(beta[j]));

  out[bA*64 + j] = o.x;
  if (bB < B) out[bB*64 + j] = o.y;
}

// ---------------------------------------------------------------------------
extern "C" void kernel_launch(void* const* d_in, const int* in_sizes, int n_in,
                              void* d_out, int out_size, void* d_ws, size_t ws_size,
                              hipStream_t stream)
{
  const float* x       = (const float*)d_in[0];
  const float* weights = (const float*)d_in[1];
  const float* Wm      = (const float*)d_in[2];
  const float* bias    = (const float*)d_in[3];
  const float* gamma   = (const float*)d_in[4];
  const float* beta    = (const float*)d_in[5];
  float* out   = (float*)d_out;
  float* gates = (float*)d_ws;   // 16 gates * 8 floats

  const int B = in_sizes[0] / 8;

  hipLaunchKernelGGL(qbranch_setup, dim3(1), dim3(64), 0, stream, weights, gates);
  hipLaunchKernelGGL(qbranch_main, dim3((B + 7) / 8), dim3(256), 0, stream,
                     x, gates, Wm, bias, gamma, beta, out, B);
}